// Round 7
// baseline (329.838 us; speedup 1.0000x reference)
//
#include <hip/hip_runtime.h>

#define IN_CH 16
#define HID 128
#define HEADS 4
#define NEG 0.2f
#define LN_EPS 1e-5f
#define BCAP 8192  // max edges per 256-node bucket (mean ~4400, +55 sigma)

typedef short bf16x8 __attribute__((ext_vector_type(8)));
typedef float f32x4 __attribute__((ext_vector_type(4)));

__device__ __forceinline__ float bf2f(unsigned short u) {
  return __uint_as_float(((unsigned)u) << 16);
}
__device__ __forceinline__ unsigned short f2bf(float f) {
  unsigned u = __float_as_uint(f);
  unsigned r = (u + 0x7fffu + ((u >> 16) & 1u)) >> 16;  // RNE
  return (unsigned short)r;
}
// sign-extended byte -> float. sh in {0,8,16,24}.
__device__ __forceinline__ float sb(unsigned v, int sh) {
  return (float)((int)(v << (24 - sh)) >> 24);
}

// ---------------------------------------------------------------------------
// h1 = x @ W1 -> int8 (per-node scale), fused attention logits.
// 8 nodes/block, W1 staged in LDS. rec[n*8] = {asrc[0..3], scale, pad}.
// (R6-verified)
// ---------------------------------------------------------------------------
__global__ __launch_bounds__(256) void k_gemm1(
    const float* __restrict__ x, const float* __restrict__ W1,
    const float* __restrict__ a_src, const float* __restrict__ a_dst,
    signed char* __restrict__ hq, float* __restrict__ rec,
    float* __restrict__ adst, int N) {
  __shared__ float w1s[IN_CH][HID];
  __shared__ float xsh[8][IN_CH];
  int tid = threadIdx.x;
  int nb = blockIdx.x * 8;
  for (int i = tid; i < IN_CH * HID; i += 256) ((float*)w1s)[i] = W1[i];
  if (tid < 128) {
    int nl = tid >> 4, k = tid & 15;
    int n = nb + nl;
    xsh[nl][k] = (n < N) ? x[n * IN_CH + k] : 0.f;
  }
  __syncthreads();
  int nl = tid >> 5;
  int l32 = tid & 31;
  int c0 = l32 << 2;
  int n = nb + nl;
  float4 acc = make_float4(0.f, 0.f, 0.f, 0.f);
#pragma unroll
  for (int k = 0; k < IN_CH; ++k) {
    float xv = xsh[nl][k];
    float4 wv = *(const float4*)(&w1s[k][c0]);
    acc.x += xv * wv.x;
    acc.y += xv * wv.y;
    acc.z += xv * wv.z;
    acc.w += xv * wv.w;
  }
  float4 as4 = *(const float4*)(a_src + c0);
  float4 ad4 = *(const float4*)(a_dst + c0);
  float av = acc.x * as4.x + acc.y * as4.y + acc.z * as4.z + acc.w * as4.w;
  float dv = acc.x * ad4.x + acc.y * ad4.y + acc.z * ad4.z + acc.w * ad4.w;
  av += __shfl_xor(av, 1);
  av += __shfl_xor(av, 2);
  av += __shfl_xor(av, 4);
  dv += __shfl_xor(dv, 1);
  dv += __shfl_xor(dv, 2);
  dv += __shfl_xor(dv, 4);
  float m = fmaxf(fmaxf(fabsf(acc.x), fabsf(acc.y)),
                  fmaxf(fabsf(acc.z), fabsf(acc.w)));
#pragma unroll
  for (int o = 1; o < 32; o <<= 1) m = fmaxf(m, __shfl_xor(m, o));
  if (n < N) {
    float rs = (m > 0.f) ? 127.f / m : 0.f;
    int b0 = __float2int_rn(acc.x * rs) & 255;
    int b1 = __float2int_rn(acc.y * rs) & 255;
    int b2 = __float2int_rn(acc.z * rs) & 255;
    int b3 = __float2int_rn(acc.w * rs) & 255;
    *(unsigned*)(hq + (size_t)n * HID + c0) =
        (unsigned)(b0 | (b1 << 8) | (b2 << 16) | (b3 << 24));
    if ((l32 & 7) == 0) {
      rec[n * 8 + (l32 >> 3)] = av;
      adst[n * HEADS + (l32 >> 3)] = dv;
    }
    if (l32 == 0) rec[n * 8 + 4] = m * (1.f / 127.f);
  }
}

// ---------------------------------------------------------------------------
// CSR build, pass A: per-(bucket, block) histogram. (R5-verified)
// ---------------------------------------------------------------------------
__global__ __launch_bounds__(256) void k_hist(
    const int* __restrict__ ei, int E, int Etot, int NBK, int NBLK,
    int* __restrict__ bcnt) {
  __shared__ int lh[512];
  int blk = blockIdx.x;
  for (int i = threadIdx.x; i < 512; i += 256) lh[i] = 0;
  __syncthreads();
  int s0 = blk * 8192, s1 = min(s0 + 8192, Etot);
  for (int e = s0 + threadIdx.x; e < s1; e += 256) {
    int d = (e < E) ? ei[E + e] : (e - E);
    atomicAdd(&lh[d >> 8], 1);
  }
  __syncthreads();
  for (int i = threadIdx.x; i < NBK; i += 256) bcnt[i * NBLK + blk] = lh[i];
}

__global__ __launch_bounds__(256) void k_scan1(
    const int* __restrict__ deg, int* __restrict__ part, int* __restrict__ aux,
    int N) {
  int i = blockIdx.x * 256 + threadIdx.x;
  int v = (i < N) ? deg[i] : 0;
  int lane = threadIdx.x & 63, w = threadIdx.x >> 6;
  int inc = v;
#pragma unroll
  for (int o = 1; o < 64; o <<= 1) {
    int t = __shfl_up(inc, o, 64);
    if (lane >= o) inc += t;
  }
  __shared__ int wsum[4];
  if (lane == 63) wsum[w] = inc;
  __syncthreads();
  int woff = 0;
#pragma unroll
  for (int k = 0; k < 4; ++k)
    if (k < w) woff += wsum[k];
  if (i < N) part[i] = woff + inc - v;
  if (threadIdx.x == 255) aux[blockIdx.x] = woff + inc;
}

__global__ __launch_bounds__(512) void k_scan2(int* __restrict__ aux, int nb) {
  int i = threadIdx.x;
  int v = (i < nb) ? aux[i] : 0;
  int lane = i & 63, w = i >> 6;
  int inc = v;
#pragma unroll
  for (int o = 1; o < 64; o <<= 1) {
    int t = __shfl_up(inc, o, 64);
    if (lane >= o) inc += t;
  }
  __shared__ int wsum[8];
  if (lane == 63) wsum[w] = inc;
  __syncthreads();
  int woff = 0;
#pragma unroll
  for (int k = 0; k < 8; ++k)
    if (k < w) woff += wsum[k];
  if (i < nb) aux[i] = woff + inc - v;
}

__global__ __launch_bounds__(256) void k_scan3g(
    const int* __restrict__ part, const int* __restrict__ aux,
    int* __restrict__ out, int M) {
  int i = blockIdx.x * 256 + threadIdx.x;
  if (i < M) out[i] = part[i] + aux[blockIdx.x];
}

// ---------------------------------------------------------------------------
// CSR build, pass C: bucket-contiguous placement. (R5-verified)
// ---------------------------------------------------------------------------
__global__ __launch_bounds__(256) void k_bucket(
    const int* __restrict__ ei, const int* __restrict__ bpre, int E, int Etot,
    int NBK, int NBLK, unsigned* __restrict__ bbuf) {
  __shared__ int lc[512];
  int blk = blockIdx.x;
  for (int i = threadIdx.x; i < NBK; i += 256) lc[i] = bpre[i * NBLK + blk];
  __syncthreads();
  int s0 = blk * 8192, s1 = min(s0 + 8192, Etot);
  for (int e = s0 + threadIdx.x; e < s1; e += 256) {
    int d = (e < E) ? ei[E + e] : (e - E);
    int s = (e < E) ? ei[e] : d;
    int pos = atomicAdd(&lc[d >> 8], 1);
    bbuf[pos] = ((unsigned)s << 8) | (unsigned)(d & 255);
  }
}

// ---------------------------------------------------------------------------
// CSR build, pass D: per-bucket LDS sort -> rowstart + coalesced csr_src.
// (R5-verified)
// ---------------------------------------------------------------------------
__global__ __launch_bounds__(256) void k_build(
    const unsigned* __restrict__ bbuf, const int* __restrict__ bpre,
    int* __restrict__ rowstart, int* __restrict__ csr_src, int N, int Etot,
    int NBK, int NBLK) {
  __shared__ int ldeg[256], lcur[256], wsum[4];
  __shared__ int lout[BCAP];
  int bin = blockIdx.x;
  int base = bpre[bin * NBLK];
  int next = (bin + 1 < NBK) ? bpre[(bin + 1) * NBLK] : Etot;
  int cnt = next - base;
  if (cnt > BCAP) cnt = BCAP;
  int tid = threadIdx.x;
  ldeg[tid] = 0;
  __syncthreads();
  for (int i = tid; i < cnt; i += 256)
    atomicAdd(&ldeg[bbuf[base + i] & 255u], 1);
  __syncthreads();
  int v = ldeg[tid];
  int lane = tid & 63, wv = tid >> 6;
  int inc = v;
#pragma unroll
  for (int o = 1; o < 64; o <<= 1) {
    int t = __shfl_up(inc, o, 64);
    if (lane >= o) inc += t;
  }
  if (lane == 63) wsum[wv] = inc;
  __syncthreads();
  int woff = 0;
#pragma unroll
  for (int k = 0; k < 4; ++k)
    if (k < wv) woff += wsum[k];
  int pre = woff + inc - v;
  int node = bin * 256 + tid;
  if (node < N) rowstart[node] = base + pre;
  lcur[tid] = pre;
  __syncthreads();
  for (int i = tid; i < cnt; i += 256) {
    unsigned u = bbuf[base + i];
    int p = atomicAdd(&lcur[u & 255u], 1);
    lout[p] = (int)(u >> 8);
  }
  __syncthreads();
  for (int i = tid; i < cnt; i += 256) csr_src[base + i] = lout[i];
  if (bin == 0 && tid == 0) rowstart[N] = Etot;
}

// ---------------------------------------------------------------------------
// Fused GAT agg + bias + ELU + LN, layer 1 (4 heads). int8 payload.
// 8 lanes/node, 16 channels/lane, uint4 gathers, 8-edge masked unroll.
// 64 edges in flight per wave (2x R6) -> latency hiding.
// ---------------------------------------------------------------------------
__global__ __launch_bounds__(256) void k_agg1(
    const int* __restrict__ rowstart, const int* __restrict__ csr_src,
    const float* __restrict__ rec, const float* __restrict__ adst,
    const signed char* __restrict__ hq, const float* __restrict__ bias,
    const float* __restrict__ g, const float* __restrict__ beta,
    unsigned short* __restrict__ outb, int N) {
  int d = blockIdx.x * 32 + (threadIdx.x >> 3);
  if (d >= N) return;
  int lane = threadIdx.x & 7;
  int c0 = lane << 4;  // 16 channels per lane
  int hd = lane >> 1;  // head = c0/32
  float ad = adst[d * HEADS + hd];
  int beg = rowstart[d], end = rowstart[d + 1];
  float a[16] = {};
  float wsum = 0.f;
  for (int i = beg; i < end; i += 8) {
    int s[8];
#pragma unroll
    for (int j = 0; j < 8; ++j) {
      int e = i + j;
      s[j] = csr_src[e < end ? e : end - 1];
    }
    float lg[8], sc[8];
    uint4 p[8];
#pragma unroll
    for (int j = 0; j < 8; ++j) {
      lg[j] = rec[s[j] * 8 + hd];
      sc[j] = rec[s[j] * 8 + 4];
    }
#pragma unroll
    for (int j = 0; j < 8; ++j)
      p[j] = *(const uint4*)(hq + (size_t)s[j] * HID + c0);
#pragma unroll
    for (int j = 0; j < 8; ++j) {
      float v = lg[j] + ad;
      v = v < 0.f ? NEG * v : v;
      float ex = __expf(v);
      float w = (i + j < end) ? ex : 0.f;
      wsum += w;
      float ws = w * sc[j];
      a[0] += ws * sb(p[j].x, 0);
      a[1] += ws * sb(p[j].x, 8);
      a[2] += ws * sb(p[j].x, 16);
      a[3] += ws * sb(p[j].x, 24);
      a[4] += ws * sb(p[j].y, 0);
      a[5] += ws * sb(p[j].y, 8);
      a[6] += ws * sb(p[j].y, 16);
      a[7] += ws * sb(p[j].y, 24);
      a[8] += ws * sb(p[j].z, 0);
      a[9] += ws * sb(p[j].z, 8);
      a[10] += ws * sb(p[j].z, 16);
      a[11] += ws * sb(p[j].z, 24);
      a[12] += ws * sb(p[j].w, 0);
      a[13] += ws * sb(p[j].w, 8);
      a[14] += ws * sb(p[j].w, 16);
      a[15] += ws * sb(p[j].w, 24);
    }
  }
  float rw = 1.f / wsum;
  float v[16];
#pragma unroll
  for (int k = 0; k < 16; ++k) {
    float t = a[k] * rw + bias[c0 + k];
    v[k] = t > 0.f ? t : (__expf(t) - 1.f);
  }
  float s1 = 0.f, s2 = 0.f;
#pragma unroll
  for (int k = 0; k < 16; ++k) {
    s1 += v[k];
    s2 += v[k] * v[k];
  }
#pragma unroll
  for (int o = 4; o > 0; o >>= 1) {
    s1 += __shfl_down(s1, o, 8);
    s2 += __shfl_down(s2, o, 8);
  }
  s1 = __shfl(s1, 0, 8);
  s2 = __shfl(s2, 0, 8);
  float mu = s1 * (1.f / HID);
  float var = s2 * (1.f / HID) - mu * mu;
  float inv = rsqrtf(var + LN_EPS);
  unsigned q[8];
#pragma unroll
  for (int k = 0; k < 8; ++k) {
    unsigned lo = f2bf((v[2 * k] - mu) * inv * g[c0 + 2 * k] + beta[c0 + 2 * k]);
    unsigned hi =
        f2bf((v[2 * k + 1] - mu) * inv * g[c0 + 2 * k + 1] + beta[c0 + 2 * k + 1]);
    q[k] = lo | (hi << 16);
  }
  *(uint4*)(outb + (size_t)d * HID + c0) = make_uint4(q[0], q[1], q[2], q[3]);
  *(uint4*)(outb + (size_t)d * HID + c0 + 8) = make_uint4(q[4], q[5], q[6], q[7]);
}

// ---------------------------------------------------------------------------
// Fused GAT agg + bias + ELU + LN, layer 2 (1 head). int8 payload,
// rec2 = {asrc, scale}. 8 lanes/node, 16 ch/lane, 8-edge masked unroll.
// ---------------------------------------------------------------------------
__global__ __launch_bounds__(256) void k_agg2(
    const int* __restrict__ rowstart, const int* __restrict__ csr_src,
    const float2* __restrict__ rec2, const float* __restrict__ adst,
    const signed char* __restrict__ hq2, const float* __restrict__ bias,
    const float* __restrict__ g, const float* __restrict__ beta,
    float* __restrict__ out, int N) {
  int d = blockIdx.x * 32 + (threadIdx.x >> 3);
  if (d >= N) return;
  int lane = threadIdx.x & 7;
  int c0 = lane << 4;
  float ad = adst[d];
  int beg = rowstart[d], end = rowstart[d + 1];
  float a[16] = {};
  float wsum = 0.f;
  for (int i = beg; i < end; i += 8) {
    int s[8];
#pragma unroll
    for (int j = 0; j < 8; ++j) {
      int e = i + j;
      s[j] = csr_src[e < end ? e : end - 1];
    }
    float2 r[8];
    uint4 p[8];
#pragma unroll
    for (int j = 0; j < 8; ++j) r[j] = rec2[s[j]];
#pragma unroll
    for (int j = 0; j < 8; ++j)
      p[j] = *(const uint4*)(hq2 + (size_t)s[j] * HID + c0);
#pragma unroll
    for (int j = 0; j < 8; ++j) {
      float v = r[j].x + ad;
      v = v < 0.f ? NEG * v : v;
      float ex = __expf(v);
      float w = (i + j < end) ? ex : 0.f;
      wsum += w;
      float ws = w * r[j].y;
      a[0] += ws * sb(p[j].x, 0);
      a[1] += ws * sb(p[j].x, 8);
      a[2] += ws * sb(p[j].x, 16);
      a[3] += ws * sb(p[j].x, 24);
      a[4] += ws * sb(p[j].y, 0);
      a[5] += ws * sb(p[j].y, 8);
      a[6] += ws * sb(p[j].y, 16);
      a[7] += ws * sb(p[j].y, 24);
      a[8] += ws * sb(p[j].z, 0);
      a[9] += ws * sb(p[j].z, 8);
      a[10] += ws * sb(p[j].z, 16);
      a[11] += ws * sb(p[j].z, 24);
      a[12] += ws * sb(p[j].w, 0);
      a[13] += ws * sb(p[j].w, 8);
      a[14] += ws * sb(p[j].w, 16);
      a[15] += ws * sb(p[j].w, 24);
    }
  }
  float rw = 1.f / wsum;
  float v[16];
#pragma unroll
  for (int k = 0; k < 16; ++k) {
    float t = a[k] * rw + bias[c0 + k];
    v[k] = t > 0.f ? t : (__expf(t) - 1.f);
  }
  float s1 = 0.f, s2 = 0.f;
#pragma unroll
  for (int k = 0; k < 16; ++k) {
    s1 += v[k];
    s2 += v[k] * v[k];
  }
#pragma unroll
  for (int o = 4; o > 0; o >>= 1) {
    s1 += __shfl_down(s1, o, 8);
    s2 += __shfl_down(s2, o, 8);
  }
  s1 = __shfl(s1, 0, 8);
  s2 = __shfl(s2, 0, 8);
  float mu = s1 * (1.f / HID);
  float var = s2 * (1.f / HID) - mu * mu;
  float inv = rsqrtf(var + LN_EPS);
#pragma unroll
  for (int k = 0; k < 4; ++k) {
    float4 o4;
    o4.x = (v[4 * k + 0] - mu) * inv * g[c0 + 4 * k + 0] + beta[c0 + 4 * k + 0];
    o4.y = (v[4 * k + 1] - mu) * inv * g[c0 + 4 * k + 1] + beta[c0 + 4 * k + 1];
    o4.z = (v[4 * k + 2] - mu) * inv * g[c0 + 4 * k + 2] + beta[c0 + 4 * k + 2];
    o4.w = (v[4 * k + 3] - mu) * inv * g[c0 + 4 * k + 3] + beta[c0 + 4 * k + 3];
    *(float4*)(out + (size_t)d * HID + c0 + 4 * k) = o4;
  }
}

// ---------------------------------------------------------------------------
// Pack W2 into MFMA B-fragment order, bf16 hi+lo. (R1-verified)
// ---------------------------------------------------------------------------
__global__ __launch_bounds__(256) void k_w2pack(
    const float* __restrict__ W2, unsigned short* __restrict__ w2hi,
    unsigned short* __restrict__ w2lo) {
  int idx = blockIdx.x * 256 + threadIdx.x;  // 16384 total
  int i = idx & 7;
  int lane = (idx >> 3) & 63;
  int t = (idx >> 9) & 7;
  int kb = idx >> 12;
  int k = kb * 32 + (lane >> 4) * 8 + i;
  int c = t * 16 + (lane & 15);
  float w = W2[k * HID + c];
  unsigned short hi = f2bf(w);
  float res = w - bf2f(hi);
  w2hi[idx] = hi;
  w2lo[idx] = f2bf(res);
}

// ---------------------------------------------------------------------------
// h2 = x2 @ W2 via MFMA bf16 (hi+lo split). Epilogue quantizes h2 -> int8
// per-node scale + rec2 = {asrc2, scale}; adst2 separate. (R6-verified)
// ---------------------------------------------------------------------------
__global__ __launch_bounds__(256) void k_gemm2m(
    const unsigned short* __restrict__ x2b,
    const unsigned short* __restrict__ w2hi,
    const unsigned short* __restrict__ w2lo,
    const float* __restrict__ a_src, const float* __restrict__ a_dst,
    signed char* __restrict__ hq2, float2* __restrict__ rec2,
    float* __restrict__ adst, int N) {
  __shared__ float cs[4][16][132];
  int w = threadIdx.x >> 6;
  int l = threadIdx.x & 63;
  int n0 = blockIdx.x * 128 + w * 32;
  int m = l & 15;    // A row within tile
  int kg = l >> 4;   // k-group
  int naA = n0 + m;
  if (naA >= N) naA = N - 1;  // clamp loads; garbage rows never stored
  int naB = n0 + 16 + m;
  if (naB >= N) naB = N - 1;
  const unsigned short* xA = x2b + (size_t)naA * HID + kg * 8;
  const unsigned short* xB = x2b + (size_t)naB * HID + kg * 8;
  f32x4 accA[8] = {};
  f32x4 accB[8] = {};
#pragma unroll
  for (int kb = 0; kb < 4; ++kb) {
    bf16x8 aA = *(const bf16x8*)(xA + kb * 32);
    bf16x8 aB = *(const bf16x8*)(xB + kb * 32);
#pragma unroll
    for (int t = 0; t < 8; ++t) {
      bf16x8 bl = *(const bf16x8*)(w2lo + ((kb * 8 + t) * 64 + l) * 8);
      bf16x8 bh = *(const bf16x8*)(w2hi + ((kb * 8 + t) * 64 + l) * 8);
      accA[t] = __builtin_amdgcn_mfma_f32_16x16x32_bf16(aA, bl, accA[t], 0, 0, 0);
      accA[t] = __builtin_amdgcn_mfma_f32_16x16x32_bf16(aA, bh, accA[t], 0, 0, 0);
      accB[t] = __builtin_amdgcn_mfma_f32_16x16x32_bf16(aB, bl, accB[t], 0, 0, 0);
      accB[t] = __builtin_amdgcn_mfma_f32_16x16x32_bf16(aB, bh, accB[t], 0, 0, 0);
    }
  }
  // C/D layout (measured): col = lane&15, row = (lane>>4)*4 + reg.
  auto epilog = [&](const f32x4(&acc)[8], int noff) {
#pragma unroll
    for (int t = 0; t < 8; ++t)
#pragma unroll
      for (int j = 0; j < 4; ++j) cs[w][kg * 4 + j][t * 16 + m] = acc[t][j];
    __syncthreads();
    int r2 = l & 15;
    int q = l >> 4;
    int n = n0 + noff + r2;
    const float* rowp = &cs[w][r2][0];
    float4 v[8];
    float pa = 0.f, pd = 0.f, mx = 0.f;
#pragma unroll
    for (int j = 0; j < 8; ++j) {
      int cc = q * 32 + j * 4;
      v[j] = *(const float4*)(rowp + cc);
      float4 as = *(const float4*)(a_src + cc);
      float4 av = *(const float4*)(a_dst + cc);
      pa += v[j].x * as.x + v[j].y * as.y + v[j].z * as.z + v[j].w * as.w;
      pd += v[j].x * av.x + v[j].y * av.y + v[j].z * av.z + v[j].w * av.w;
      mx = fmaxf(mx, fmaxf(fmaxf(fabsf(v[j].x), fabsf(v[j].y)),
                           fmaxf(fabsf(v[j].z), fabsf(v[j].w))));
    }
    pa += __shfl_xor(pa, 16);
    pa += __shfl_xor(pa, 32);
    pd += __shfl_xor(pd, 16);
    pd += __shfl_xor(pd, 32);
    mx = fmaxf(mx, __shfl_xor(mx, 16));
    mx = fmaxf(mx, __shfl_xor(mx, 32));
    if (n < N) {
      float rs = (mx > 0.f) ? 127.f / mx : 0.f;
      unsigned u[8];
#pragma unroll
      for (int j = 0; j < 8; ++j) {
        int b0 = __float2int_rn(v[j].x * rs) & 255;
        int b1 = __float2int_rn(v[j].y * rs) & 255;
        int b2 = __float2int_rn(v[j].z * rs) & 255;
        int b3 = __float2int_rn(v[j].w * rs) & 255;
        u[j] = (unsigned)(b0 | (b1 << 8) | (b2 << 16) | (b3 << 24));
      }
      *(uint4*)(hq2 + (size_t)n * HID + q * 32) =
          make_uint4(u[0], u[1], u[2], u[3]);
      *(uint4*)(hq2 + (size_t)n * HID + q * 32 + 16) =
          make_uint4(u[4], u[5], u[6], u[7]);
      if (q == 0) {
        rec2[n] = make_float2(pa, mx * (1.f / 127.f));
        adst[n] = pd;
      }
    }
    __syncthreads();
  };
  epilog(accA, 0);
  epilog(accB, 16);
}

extern "C" void kernel_launch(void* const* d_in, const int* in_sizes, int n_in,
                              void* d_out, int out_size, void* d_ws, size_t ws_size,
                              hipStream_t stream) {
  const float* x      = (const float*)d_in[0];
  const int*   ei     = (const int*)d_in[1];
  const float* W1     = (const float*)d_in[2];
  const float* a_src1 = (const float*)d_in[3];
  const float* a_dst1 = (const float*)d_in[4];
  const float* b1     = (const float*)d_in[5];
  const float* g1     = (const float*)d_in[6];
  const float* beta1  = (const float*)d_in[7];
  const float* W2     = (const float*)d_in[8];
  const float* a_src2 = (const float*)d_in[9];
  const float* a_dst2 = (const float*)d_in[10];
  const float* b2     = (const float*)d_in[11];
  const float* g2     = (const float*)d_in[12];
  const float* beta2  = (const float*)d_in[13];
  float* out = (float*)d_out;

  const int N = in_sizes[0] / IN_CH;
  const int E = in_sizes[1] / 2;
  const int Etot = E + N;

  // bucketed CSR geometry
  const int NBK = (N + 255) >> 8;          // buckets of 256 nodes
  const int NBLK = (Etot + 8191) >> 13;    // 8192-edge chunks
  const int M = NBK * NBLK;                // count-matrix size
  const int Mblk = (M + 255) / 256;        // scan blocks (<= 512)

  // workspace layout (separate regions; no overlays)
  unsigned char* U = (unsigned char*)d_ws;
  signed char* hq = (signed char*)U;                       // N*HID int8
  float* rec = (float*)(U + (size_t)N * HID);              // N*8 f32
  unsigned short* x2b =
      (unsigned short*)(U + (size_t)N * HID + (size_t)N * 32);  // N*HID bf16
  signed char* hq2 = (signed char*)(x2b + (size_t)N * HID);     // N*HID int8
  float2* rec2 = (float2*)(hq2 + (size_t)N * HID);         // N float2
  float* adst1 = (float*)(rec2 + N);
  float* adst2 = adst1 + (size_t)N * HEADS;
  int* rowstart = (int*)(adst2 + N);   // [N+1] padded to N+4
  int* aux      = rowstart + N + 4;    // [<=1024]
  int* bcnt     = aux + 1024;          // [M]
  int* bpart    = bcnt + M;            // [M]
  int* bpre     = bpart + M;           // [M]
  unsigned* bbuf = (unsigned*)(bpre + M);  // [Etot]
  int* csr_src  = (int*)(bbuf + Etot);     // [Etot]
  unsigned short* w2hi = (unsigned short*)(csr_src + Etot);  // [16384]
  unsigned short* w2lo = w2hi + 16384;                       // [16384]

  // ---- W2 fragment pack (independent of everything else) ----
  k_w2pack<<<64, 256, 0, stream>>>(W2, w2hi, w2lo);

  // ---- bucketed CSR build (zero global atomics) ----
  k_hist<<<NBLK, 256, 0, stream>>>(ei, E, Etot, NBK, NBLK, bcnt);
  k_scan1<<<Mblk, 256, 0, stream>>>(bcnt, bpart, aux, M);
  k_scan2<<<1, 512, 0, stream>>>(aux, Mblk);
  k_scan3g<<<Mblk, 256, 0, stream>>>(bpart, aux, bpre, M);
  k_bucket<<<NBLK, 256, 0, stream>>>(ei, bpre, E, Etot, NBK, NBLK, bbuf);
  k_build<<<NBK, 256, 0, stream>>>(bbuf, bpre, rowstart, csr_src, N, Etot,
                                   NBK, NBLK);

  // ---- Layer 1 ----
  k_gemm1<<<(N + 7) / 8, 256, 0, stream>>>(x, W1, a_src1, a_dst1, hq, rec,
                                           adst1, N);
  k_agg1<<<(N + 31) / 32, 256, 0, stream>>>(rowstart, csr_src, rec, adst1, hq,
                                            b1, g1, beta1, x2b, N);

  // ---- Layer 2 ----
  k_gemm2m<<<(N + 127) / 128, 256, 0, stream>>>(x2b, w2hi, w2lo, a_src2,
                                                a_dst2, hq2, rec2, adst2, N);
  k_agg2<<<(N + 31) / 32, 256, 0, stream>>>(rowstart, csr_src, rec2, adst2,
                                            hq2, b2, g2, beta2, out, N);
}

// Round 8
// 317.305 us; speedup vs baseline: 1.0395x; 1.0395x over previous
//
#include <hip/hip_runtime.h>

#define IN_CH 16
#define HID 128
#define HEADS 4
#define NEG 0.2f
#define LN_EPS 1e-5f
#define BCAP 8192  // max edges per 256-node bucket (mean ~4400, +55 sigma)

typedef short bf16x8 __attribute__((ext_vector_type(8)));
typedef float f32x4 __attribute__((ext_vector_type(4)));

__device__ __forceinline__ float bf2f(unsigned short u) {
  return __uint_as_float(((unsigned)u) << 16);
}
__device__ __forceinline__ unsigned short f2bf(float f) {
  unsigned u = __float_as_uint(f);
  unsigned r = (u + 0x7fffu + ((u >> 16) & 1u)) >> 16;  // RNE
  return (unsigned short)r;
}
// sign-extended byte -> float. sh in {0,8,16,24}.
__device__ __forceinline__ float sb(unsigned v, int sh) {
  return (float)((int)(v << (24 - sh)) >> 24);
}

// ---------------------------------------------------------------------------
// h1 = x @ W1 -> int8 (per-node scale), fused attention logits.
// 8 nodes/block, W1 staged in LDS. rec[n*8] = {asrc[0..3], scale, pad}.
// (R6-verified)
// ---------------------------------------------------------------------------
__global__ __launch_bounds__(256) void k_gemm1(
    const float* __restrict__ x, const float* __restrict__ W1,
    const float* __restrict__ a_src, const float* __restrict__ a_dst,
    signed char* __restrict__ hq, float* __restrict__ rec,
    float* __restrict__ adst, int N) {
  __shared__ float w1s[IN_CH][HID];
  __shared__ float xsh[8][IN_CH];
  int tid = threadIdx.x;
  int nb = blockIdx.x * 8;
  for (int i = tid; i < IN_CH * HID; i += 256) ((float*)w1s)[i] = W1[i];
  if (tid < 128) {
    int nl = tid >> 4, k = tid & 15;
    int n = nb + nl;
    xsh[nl][k] = (n < N) ? x[n * IN_CH + k] : 0.f;
  }
  __syncthreads();
  int nl = tid >> 5;
  int l32 = tid & 31;
  int c0 = l32 << 2;
  int n = nb + nl;
  float4 acc = make_float4(0.f, 0.f, 0.f, 0.f);
#pragma unroll
  for (int k = 0; k < IN_CH; ++k) {
    float xv = xsh[nl][k];
    float4 wv = *(const float4*)(&w1s[k][c0]);
    acc.x += xv * wv.x;
    acc.y += xv * wv.y;
    acc.z += xv * wv.z;
    acc.w += xv * wv.w;
  }
  float4 as4 = *(const float4*)(a_src + c0);
  float4 ad4 = *(const float4*)(a_dst + c0);
  float av = acc.x * as4.x + acc.y * as4.y + acc.z * as4.z + acc.w * as4.w;
  float dv = acc.x * ad4.x + acc.y * ad4.y + acc.z * ad4.z + acc.w * ad4.w;
  av += __shfl_xor(av, 1);
  av += __shfl_xor(av, 2);
  av += __shfl_xor(av, 4);
  dv += __shfl_xor(dv, 1);
  dv += __shfl_xor(dv, 2);
  dv += __shfl_xor(dv, 4);
  float m = fmaxf(fmaxf(fabsf(acc.x), fabsf(acc.y)),
                  fmaxf(fabsf(acc.z), fabsf(acc.w)));
#pragma unroll
  for (int o = 1; o < 32; o <<= 1) m = fmaxf(m, __shfl_xor(m, o));
  if (n < N) {
    float rs = (m > 0.f) ? 127.f / m : 0.f;
    int b0 = __float2int_rn(acc.x * rs) & 255;
    int b1 = __float2int_rn(acc.y * rs) & 255;
    int b2 = __float2int_rn(acc.z * rs) & 255;
    int b3 = __float2int_rn(acc.w * rs) & 255;
    *(unsigned*)(hq + (size_t)n * HID + c0) =
        (unsigned)(b0 | (b1 << 8) | (b2 << 16) | (b3 << 24));
    if ((l32 & 7) == 0) {
      rec[n * 8 + (l32 >> 3)] = av;
      adst[n * HEADS + (l32 >> 3)] = dv;
    }
    if (l32 == 0) rec[n * 8 + 4] = m * (1.f / 127.f);
  }
}

// ---------------------------------------------------------------------------
// CSR build, pass A: per-(bucket, block) histogram. (R5-verified)
// ---------------------------------------------------------------------------
__global__ __launch_bounds__(256) void k_hist(
    const int* __restrict__ ei, int E, int Etot, int NBK, int NBLK,
    int* __restrict__ bcnt) {
  __shared__ int lh[512];
  int blk = blockIdx.x;
  for (int i = threadIdx.x; i < 512; i += 256) lh[i] = 0;
  __syncthreads();
  int s0 = blk * 8192, s1 = min(s0 + 8192, Etot);
  for (int e = s0 + threadIdx.x; e < s1; e += 256) {
    int d = (e < E) ? ei[E + e] : (e - E);
    atomicAdd(&lh[d >> 8], 1);
  }
  __syncthreads();
  for (int i = threadIdx.x; i < NBK; i += 256) bcnt[i * NBLK + blk] = lh[i];
}

__global__ __launch_bounds__(256) void k_scan1(
    const int* __restrict__ deg, int* __restrict__ part, int* __restrict__ aux,
    int N) {
  int i = blockIdx.x * 256 + threadIdx.x;
  int v = (i < N) ? deg[i] : 0;
  int lane = threadIdx.x & 63, w = threadIdx.x >> 6;
  int inc = v;
#pragma unroll
  for (int o = 1; o < 64; o <<= 1) {
    int t = __shfl_up(inc, o, 64);
    if (lane >= o) inc += t;
  }
  __shared__ int wsum[4];
  if (lane == 63) wsum[w] = inc;
  __syncthreads();
  int woff = 0;
#pragma unroll
  for (int k = 0; k < 4; ++k)
    if (k < w) woff += wsum[k];
  if (i < N) part[i] = woff + inc - v;
  if (threadIdx.x == 255) aux[blockIdx.x] = woff + inc;
}

__global__ __launch_bounds__(512) void k_scan2(int* __restrict__ aux, int nb) {
  int i = threadIdx.x;
  int v = (i < nb) ? aux[i] : 0;
  int lane = i & 63, w = i >> 6;
  int inc = v;
#pragma unroll
  for (int o = 1; o < 64; o <<= 1) {
    int t = __shfl_up(inc, o, 64);
    if (lane >= o) inc += t;
  }
  __shared__ int wsum[8];
  if (lane == 63) wsum[w] = inc;
  __syncthreads();
  int woff = 0;
#pragma unroll
  for (int k = 0; k < 8; ++k)
    if (k < w) woff += wsum[k];
  if (i < nb) aux[i] = woff + inc - v;
}

__global__ __launch_bounds__(256) void k_scan3g(
    const int* __restrict__ part, const int* __restrict__ aux,
    int* __restrict__ out, int M) {
  int i = blockIdx.x * 256 + threadIdx.x;
  if (i < M) out[i] = part[i] + aux[blockIdx.x];
}

// ---------------------------------------------------------------------------
// CSR build, pass C: bucket-contiguous placement. (R5-verified)
// ---------------------------------------------------------------------------
__global__ __launch_bounds__(256) void k_bucket(
    const int* __restrict__ ei, const int* __restrict__ bpre, int E, int Etot,
    int NBK, int NBLK, unsigned* __restrict__ bbuf) {
  __shared__ int lc[512];
  int blk = blockIdx.x;
  for (int i = threadIdx.x; i < NBK; i += 256) lc[i] = bpre[i * NBLK + blk];
  __syncthreads();
  int s0 = blk * 8192, s1 = min(s0 + 8192, Etot);
  for (int e = s0 + threadIdx.x; e < s1; e += 256) {
    int d = (e < E) ? ei[E + e] : (e - E);
    int s = (e < E) ? ei[e] : d;
    int pos = atomicAdd(&lc[d >> 8], 1);
    bbuf[pos] = ((unsigned)s << 8) | (unsigned)(d & 255);
  }
}

// ---------------------------------------------------------------------------
// CSR build, pass D: per-bucket LDS sort -> rowstart + coalesced csr_src.
// (R5-verified)
// ---------------------------------------------------------------------------
__global__ __launch_bounds__(256) void k_build(
    const unsigned* __restrict__ bbuf, const int* __restrict__ bpre,
    int* __restrict__ rowstart, int* __restrict__ csr_src, int N, int Etot,
    int NBK, int NBLK) {
  __shared__ int ldeg[256], lcur[256], wsum[4];
  __shared__ int lout[BCAP];
  int bin = blockIdx.x;
  int base = bpre[bin * NBLK];
  int next = (bin + 1 < NBK) ? bpre[(bin + 1) * NBLK] : Etot;
  int cnt = next - base;
  if (cnt > BCAP) cnt = BCAP;
  int tid = threadIdx.x;
  ldeg[tid] = 0;
  __syncthreads();
  for (int i = tid; i < cnt; i += 256)
    atomicAdd(&ldeg[bbuf[base + i] & 255u], 1);
  __syncthreads();
  int v = ldeg[tid];
  int lane = tid & 63, wv = tid >> 6;
  int inc = v;
#pragma unroll
  for (int o = 1; o < 64; o <<= 1) {
    int t = __shfl_up(inc, o, 64);
    if (lane >= o) inc += t;
  }
  if (lane == 63) wsum[wv] = inc;
  __syncthreads();
  int woff = 0;
#pragma unroll
  for (int k = 0; k < 4; ++k)
    if (k < wv) woff += wsum[k];
  int pre = woff + inc - v;
  int node = bin * 256 + tid;
  if (node < N) rowstart[node] = base + pre;
  lcur[tid] = pre;
  __syncthreads();
  for (int i = tid; i < cnt; i += 256) {
    unsigned u = bbuf[base + i];
    int p = atomicAdd(&lcur[u & 255u], 1);
    lout[p] = (int)(u >> 8);
  }
  __syncthreads();
  for (int i = tid; i < cnt; i += 256) csr_src[base + i] = lout[i];
  if (bin == 0 && tid == 0) rowstart[N] = Etot;
}

// ---------------------------------------------------------------------------
// Fused GAT agg + bias + ELU + LN, layer 1 (4 heads). int8 payload.
// R6 structure (16 lanes/node, uint2 gathers) + 1-chunk-ahead software
// pipeline: payload gathers for chunk i+1 and indices for chunk i+2 are
// issued before chunk i's FMAs, breaking the csr->gather->use chain.
// ---------------------------------------------------------------------------
__global__ __launch_bounds__(256) void k_agg1(
    const int* __restrict__ rowstart, const int* __restrict__ csr_src,
    const float* __restrict__ rec, const float* __restrict__ adst,
    const signed char* __restrict__ hq, const float* __restrict__ bias,
    const float* __restrict__ g, const float* __restrict__ beta,
    unsigned short* __restrict__ outb, int N) {
  int d = blockIdx.x * 16 + (threadIdx.x >> 4);
  if (d >= N) return;
  int lane = threadIdx.x & 15;
  int c0 = lane << 3;  // 8 channels per lane
  int hd = lane >> 2;  // head = c0/32
  float ad = adst[d * HEADS + hd];
  int beg = rowstart[d], end = rowstart[d + 1];
  float a0 = 0.f, a1 = 0.f, a2 = 0.f, a3 = 0.f;
  float a4 = 0.f, a5 = 0.f, a6 = 0.f, a7 = 0.f, wsum = 0.f;
  // pipeline prologue: s two chunks ahead, payload one chunk ahead
  int s0[8], s1[8];
  uint2 p0[8];
#pragma unroll
  for (int j = 0; j < 8; ++j) {
    int e = beg + j;
    s0[j] = csr_src[e < end ? e : end - 1];
  }
#pragma unroll
  for (int j = 0; j < 8; ++j) {
    int e = beg + 8 + j;
    s1[j] = csr_src[e < end ? e : end - 1];
  }
#pragma unroll
  for (int j = 0; j < 8; ++j)
    p0[j] = *(const uint2*)(hq + (size_t)s0[j] * HID + c0);
  for (int i = beg; i < end; i += 8) {
    // current-chunk rec gathers (L2-resident, modest lead)
    float lg[8], sc[8];
#pragma unroll
    for (int j = 0; j < 8; ++j) {
      lg[j] = rec[s0[j] * 8 + hd];
      sc[j] = rec[s0[j] * 8 + 4];
    }
    // next-chunk payload gathers (full compute-phase lead)
    uint2 p1[8];
#pragma unroll
    for (int j = 0; j < 8; ++j)
      p1[j] = *(const uint2*)(hq + (size_t)s1[j] * HID + c0);
    // chunk i+2 indices
    int s2[8];
#pragma unroll
    for (int j = 0; j < 8; ++j) {
      int e = i + 16 + j;
      s2[j] = csr_src[e < end ? e : end - 1];
    }
    // compute chunk i (payload p0 has been in flight a full iteration)
#pragma unroll
    for (int j = 0; j < 8; ++j) {
      float v = lg[j] + ad;
      v = v < 0.f ? NEG * v : v;
      float ex = __expf(v);
      float w = (i + j < end) ? ex : 0.f;
      wsum += w;
      float ws = w * sc[j];
      a0 += ws * sb(p0[j].x, 0);
      a1 += ws * sb(p0[j].x, 8);
      a2 += ws * sb(p0[j].x, 16);
      a3 += ws * sb(p0[j].x, 24);
      a4 += ws * sb(p0[j].y, 0);
      a5 += ws * sb(p0[j].y, 8);
      a6 += ws * sb(p0[j].y, 16);
      a7 += ws * sb(p0[j].y, 24);
    }
    // rotate
#pragma unroll
    for (int j = 0; j < 8; ++j) {
      s0[j] = s1[j];
      s1[j] = s2[j];
      p0[j] = p1[j];
    }
  }
  float rw = 1.f / wsum;
  float v0 = a0 * rw + bias[c0 + 0];
  float v1 = a1 * rw + bias[c0 + 1];
  float v2 = a2 * rw + bias[c0 + 2];
  float v3 = a3 * rw + bias[c0 + 3];
  float v4 = a4 * rw + bias[c0 + 4];
  float v5 = a5 * rw + bias[c0 + 5];
  float v6 = a6 * rw + bias[c0 + 6];
  float v7 = a7 * rw + bias[c0 + 7];
  v0 = v0 > 0.f ? v0 : (__expf(v0) - 1.f);
  v1 = v1 > 0.f ? v1 : (__expf(v1) - 1.f);
  v2 = v2 > 0.f ? v2 : (__expf(v2) - 1.f);
  v3 = v3 > 0.f ? v3 : (__expf(v3) - 1.f);
  v4 = v4 > 0.f ? v4 : (__expf(v4) - 1.f);
  v5 = v5 > 0.f ? v5 : (__expf(v5) - 1.f);
  v6 = v6 > 0.f ? v6 : (__expf(v6) - 1.f);
  v7 = v7 > 0.f ? v7 : (__expf(v7) - 1.f);
  float s1r = ((v0 + v1) + (v2 + v3)) + ((v4 + v5) + (v6 + v7));
  float s2r = ((v0 * v0 + v1 * v1) + (v2 * v2 + v3 * v3)) +
              ((v4 * v4 + v5 * v5) + (v6 * v6 + v7 * v7));
#pragma unroll
  for (int o = 8; o > 0; o >>= 1) {
    s1r += __shfl_down(s1r, o, 16);
    s2r += __shfl_down(s2r, o, 16);
  }
  s1r = __shfl(s1r, 0, 16);
  s2r = __shfl(s2r, 0, 16);
  float mu = s1r * (1.f / HID);
  float var = s2r * (1.f / HID) - mu * mu;
  float inv = rsqrtf(var + LN_EPS);
  ushort4 q0, q1;
  q0.x = f2bf((v0 - mu) * inv * g[c0 + 0] + beta[c0 + 0]);
  q0.y = f2bf((v1 - mu) * inv * g[c0 + 1] + beta[c0 + 1]);
  q0.z = f2bf((v2 - mu) * inv * g[c0 + 2] + beta[c0 + 2]);
  q0.w = f2bf((v3 - mu) * inv * g[c0 + 3] + beta[c0 + 3]);
  q1.x = f2bf((v4 - mu) * inv * g[c0 + 4] + beta[c0 + 4]);
  q1.y = f2bf((v5 - mu) * inv * g[c0 + 5] + beta[c0 + 5]);
  q1.z = f2bf((v6 - mu) * inv * g[c0 + 6] + beta[c0 + 6]);
  q1.w = f2bf((v7 - mu) * inv * g[c0 + 7] + beta[c0 + 7]);
  *(ushort4*)(outb + (size_t)d * HID + c0) = q0;
  *(ushort4*)(outb + (size_t)d * HID + c0 + 4) = q1;
}

// ---------------------------------------------------------------------------
// Fused GAT agg + bias + ELU + LN, layer 2 (1 head). int8 payload,
// rec2 = {asrc, scale}. R6 structure + same software pipeline as agg1.
// ---------------------------------------------------------------------------
__global__ __launch_bounds__(256) void k_agg2(
    const int* __restrict__ rowstart, const int* __restrict__ csr_src,
    const float2* __restrict__ rec2, const float* __restrict__ adst,
    const signed char* __restrict__ hq2, const float* __restrict__ bias,
    const float* __restrict__ g, const float* __restrict__ beta,
    float* __restrict__ out, int N) {
  int d = blockIdx.x * 16 + (threadIdx.x >> 4);
  if (d >= N) return;
  int lane = threadIdx.x & 15;
  int c0 = lane << 3;
  float ad = adst[d];
  int beg = rowstart[d], end = rowstart[d + 1];
  float a0 = 0.f, a1 = 0.f, a2 = 0.f, a3 = 0.f;
  float a4 = 0.f, a5 = 0.f, a6 = 0.f, a7 = 0.f, wsum = 0.f;
  int s0[8], s1[8];
  uint2 p0[8];
#pragma unroll
  for (int j = 0; j < 8; ++j) {
    int e = beg + j;
    s0[j] = csr_src[e < end ? e : end - 1];
  }
#pragma unroll
  for (int j = 0; j < 8; ++j) {
    int e = beg + 8 + j;
    s1[j] = csr_src[e < end ? e : end - 1];
  }
#pragma unroll
  for (int j = 0; j < 8; ++j)
    p0[j] = *(const uint2*)(hq2 + (size_t)s0[j] * HID + c0);
  for (int i = beg; i < end; i += 8) {
    float2 r[8];
#pragma unroll
    for (int j = 0; j < 8; ++j) r[j] = rec2[s0[j]];
    uint2 p1[8];
#pragma unroll
    for (int j = 0; j < 8; ++j)
      p1[j] = *(const uint2*)(hq2 + (size_t)s1[j] * HID + c0);
    int s2[8];
#pragma unroll
    for (int j = 0; j < 8; ++j) {
      int e = i + 16 + j;
      s2[j] = csr_src[e < end ? e : end - 1];
    }
#pragma unroll
    for (int j = 0; j < 8; ++j) {
      float v = r[j].x + ad;
      v = v < 0.f ? NEG * v : v;
      float ex = __expf(v);
      float w = (i + j < end) ? ex : 0.f;
      wsum += w;
      float ws = w * r[j].y;
      a0 += ws * sb(p0[j].x, 0);
      a1 += ws * sb(p0[j].x, 8);
      a2 += ws * sb(p0[j].x, 16);
      a3 += ws * sb(p0[j].x, 24);
      a4 += ws * sb(p0[j].y, 0);
      a5 += ws * sb(p0[j].y, 8);
      a6 += ws * sb(p0[j].y, 16);
      a7 += ws * sb(p0[j].y, 24);
    }
#pragma unroll
    for (int j = 0; j < 8; ++j) {
      s0[j] = s1[j];
      s1[j] = s2[j];
      p0[j] = p1[j];
    }
  }
  float rw = 1.f / wsum;
  float v0 = a0 * rw + bias[c0 + 0];
  float v1 = a1 * rw + bias[c0 + 1];
  float v2 = a2 * rw + bias[c0 + 2];
  float v3 = a3 * rw + bias[c0 + 3];
  float v4 = a4 * rw + bias[c0 + 4];
  float v5 = a5 * rw + bias[c0 + 5];
  float v6 = a6 * rw + bias[c0 + 6];
  float v7 = a7 * rw + bias[c0 + 7];
  v0 = v0 > 0.f ? v0 : (__expf(v0) - 1.f);
  v1 = v1 > 0.f ? v1 : (__expf(v1) - 1.f);
  v2 = v2 > 0.f ? v2 : (__expf(v2) - 1.f);
  v3 = v3 > 0.f ? v3 : (__expf(v3) - 1.f);
  v4 = v4 > 0.f ? v4 : (__expf(v4) - 1.f);
  v5 = v5 > 0.f ? v5 : (__expf(v5) - 1.f);
  v6 = v6 > 0.f ? v6 : (__expf(v6) - 1.f);
  v7 = v7 > 0.f ? v7 : (__expf(v7) - 1.f);
  float s1r = ((v0 + v1) + (v2 + v3)) + ((v4 + v5) + (v6 + v7));
  float s2r = ((v0 * v0 + v1 * v1) + (v2 * v2 + v3 * v3)) +
              ((v4 * v4 + v5 * v5) + (v6 * v6 + v7 * v7));
#pragma unroll
  for (int o = 8; o > 0; o >>= 1) {
    s1r += __shfl_down(s1r, o, 16);
    s2r += __shfl_down(s2r, o, 16);
  }
  s1r = __shfl(s1r, 0, 16);
  s2r = __shfl(s2r, 0, 16);
  float mu = s1r * (1.f / HID);
  float var = s2r * (1.f / HID) - mu * mu;
  float inv = rsqrtf(var + LN_EPS);
  float4 o0, o1;
  o0.x = (v0 - mu) * inv * g[c0 + 0] + beta[c0 + 0];
  o0.y = (v1 - mu) * inv * g[c0 + 1] + beta[c0 + 1];
  o0.z = (v2 - mu) * inv * g[c0 + 2] + beta[c0 + 2];
  o0.w = (v3 - mu) * inv * g[c0 + 3] + beta[c0 + 3];
  o1.x = (v4 - mu) * inv * g[c0 + 4] + beta[c0 + 4];
  o1.y = (v5 - mu) * inv * g[c0 + 5] + beta[c0 + 5];
  o1.z = (v6 - mu) * inv * g[c0 + 6] + beta[c0 + 6];
  o1.w = (v7 - mu) * inv * g[c0 + 7] + beta[c0 + 7];
  *(float4*)(out + (size_t)d * HID + c0) = o0;
  *(float4*)(out + (size_t)d * HID + c0 + 4) = o1;
}

// ---------------------------------------------------------------------------
// Pack W2 into MFMA B-fragment order, bf16 hi+lo. (R1-verified)
// ---------------------------------------------------------------------------
__global__ __launch_bounds__(256) void k_w2pack(
    const float* __restrict__ W2, unsigned short* __restrict__ w2hi,
    unsigned short* __restrict__ w2lo) {
  int idx = blockIdx.x * 256 + threadIdx.x;  // 16384 total
  int i = idx & 7;
  int lane = (idx >> 3) & 63;
  int t = (idx >> 9) & 7;
  int kb = idx >> 12;
  int k = kb * 32 + (lane >> 4) * 8 + i;
  int c = t * 16 + (lane & 15);
  float w = W2[k * HID + c];
  unsigned short hi = f2bf(w);
  float res = w - bf2f(hi);
  w2hi[idx] = hi;
  w2lo[idx] = f2bf(res);
}

// ---------------------------------------------------------------------------
// h2 = x2 @ W2 via MFMA bf16 (hi+lo split). Epilogue quantizes h2 -> int8
// per-node scale + rec2 = {asrc2, scale}; adst2 separate. (R6-verified)
// ---------------------------------------------------------------------------
__global__ __launch_bounds__(256) void k_gemm2m(
    const unsigned short* __restrict__ x2b,
    const unsigned short* __restrict__ w2hi,
    const unsigned short* __restrict__ w2lo,
    const float* __restrict__ a_src, const float* __restrict__ a_dst,
    signed char* __restrict__ hq2, float2* __restrict__ rec2,
    float* __restrict__ adst, int N) {
  __shared__ float cs[4][16][132];
  int w = threadIdx.x >> 6;
  int l = threadIdx.x & 63;
  int n0 = blockIdx.x * 128 + w * 32;
  int m = l & 15;    // A row within tile
  int kg = l >> 4;   // k-group
  int naA = n0 + m;
  if (naA >= N) naA = N - 1;  // clamp loads; garbage rows never stored
  int naB = n0 + 16 + m;
  if (naB >= N) naB = N - 1;
  const unsigned short* xA = x2b + (size_t)naA * HID + kg * 8;
  const unsigned short* xB = x2b + (size_t)naB * HID + kg * 8;
  f32x4 accA[8] = {};
  f32x4 accB[8] = {};
#pragma unroll
  for (int kb = 0; kb < 4; ++kb) {
    bf16x8 aA = *(const bf16x8*)(xA + kb * 32);
    bf16x8 aB = *(const bf16x8*)(xB + kb * 32);
#pragma unroll
    for (int t = 0; t < 8; ++t) {
      bf16x8 bl = *(const bf16x8*)(w2lo + ((kb * 8 + t) * 64 + l) * 8);
      bf16x8 bh = *(const bf16x8*)(w2hi + ((kb * 8 + t) * 64 + l) * 8);
      accA[t] = __builtin_amdgcn_mfma_f32_16x16x32_bf16(aA, bl, accA[t], 0, 0, 0);
      accA[t] = __builtin_amdgcn_mfma_f32_16x16x32_bf16(aA, bh, accA[t], 0, 0, 0);
      accB[t] = __builtin_amdgcn_mfma_f32_16x16x32_bf16(aB, bl, accB[t], 0, 0, 0);
      accB[t] = __builtin_amdgcn_mfma_f32_16x16x32_bf16(aB, bh, accB[t], 0, 0, 0);
    }
  }
  // C/D layout (measured): col = lane&15, row = (lane>>4)*4 + reg.
  auto epilog = [&](const f32x4(&acc)[8], int noff) {
#pragma unroll
    for (int t = 0; t < 8; ++t)
#pragma unroll
      for (int j = 0; j < 4; ++j) cs[w][kg * 4 + j][t * 16 + m] = acc[t][j];
    __syncthreads();
    int r2 = l & 15;
    int q = l >> 4;
    int n = n0 + noff + r2;
    const float* rowp = &cs[w][r2][0];
    float4 v[8];
    float pa = 0.f, pd = 0.f, mx = 0.f;
#pragma unroll
    for (int j = 0; j < 8; ++j) {
      int cc = q * 32 + j * 4;
      v[j] = *(const float4*)(rowp + cc);
      float4 as = *(const float4*)(a_src + cc);
      float4 av = *(const float4*)(a_dst + cc);
      pa += v[j].x * as.x + v[j].y * as.y + v[j].z * as.z + v[j].w * as.w;
      pd += v[j].x * av.x + v[j].y * av.y + v[j].z * av.z + v[j].w * av.w;
      mx = fmaxf(mx, fmaxf(fmaxf(fabsf(v[j].x), fabsf(v[j].y)),
                           fmaxf(fabsf(v[j].z), fabsf(v[j].w))));
    }
    pa += __shfl_xor(pa, 16);
    pa += __shfl_xor(pa, 32);
    pd += __shfl_xor(pd, 16);
    pd += __shfl_xor(pd, 32);
    mx = fmaxf(mx, __shfl_xor(mx, 16));
    mx = fmaxf(mx, __shfl_xor(mx, 32));
    if (n < N) {
      float rs = (mx > 0.f) ? 127.f / mx : 0.f;
      unsigned u[8];
#pragma unroll
      for (int j = 0; j < 8; ++j) {
        int b0 = __float2int_rn(v[j].x * rs) & 255;
        int b1 = __float2int_rn(v[j].y * rs) & 255;
        int b2 = __float2int_rn(v[j].z * rs) & 255;
        int b3 = __float2int_rn(v[j].w * rs) & 255;
        u[j] = (unsigned)(b0 | (b1 << 8) | (b2 << 16) | (b3 << 24));
      }
      *(uint4*)(hq2 + (size_t)n * HID + q * 32) =
          make_uint4(u[0], u[1], u[2], u[3]);
      *(uint4*)(hq2 + (size_t)n * HID + q * 32 + 16) =
          make_uint4(u[4], u[5], u[6], u[7]);
      if (q == 0) {
        rec2[n] = make_float2(pa, mx * (1.f / 127.f));
        adst[n] = pd;
      }
    }
    __syncthreads();
  };
  epilog(accA, 0);
  epilog(accB, 16);
}

extern "C" void kernel_launch(void* const* d_in, const int* in_sizes, int n_in,
                              void* d_out, int out_size, void* d_ws, size_t ws_size,
                              hipStream_t stream) {
  const float* x      = (const float*)d_in[0];
  const int*   ei     = (const int*)d_in[1];
  const float* W1     = (const float*)d_in[2];
  const float* a_src1 = (const float*)d_in[3];
  const float* a_dst1 = (const float*)d_in[4];
  const float* b1     = (const float*)d_in[5];
  const float* g1     = (const float*)d_in[6];
  const float* beta1  = (const float*)d_in[7];
  const float* W2     = (const float*)d_in[8];
  const float* a_src2 = (const float*)d_in[9];
  const float* a_dst2 = (const float*)d_in[10];
  const float* b2     = (const float*)d_in[11];
  const float* g2     = (const float*)d_in[12];
  const float* beta2  = (const float*)d_in[13];
  float* out = (float*)d_out;

  const int N = in_sizes[0] / IN_CH;
  const int E = in_sizes[1] / 2;
  const int Etot = E + N;

  // bucketed CSR geometry
  const int NBK = (N + 255) >> 8;          // buckets of 256 nodes
  const int NBLK = (Etot + 8191) >> 13;    // 8192-edge chunks
  const int M = NBK * NBLK;                // count-matrix size
  const int Mblk = (M + 255) / 256;        // scan blocks (<= 512)

  // workspace layout (separate regions; no overlays)
  unsigned char* U = (unsigned char*)d_ws;
  signed char* hq = (signed char*)U;                       // N*HID int8
  float* rec = (float*)(U + (size_t)N * HID);              // N*8 f32
  unsigned short* x2b =
      (unsigned short*)(U + (size_t)N * HID + (size_t)N * 32);  // N*HID bf16
  signed char* hq2 = (signed char*)(x2b + (size_t)N * HID);     // N*HID int8
  float2* rec2 = (float2*)(hq2 + (size_t)N * HID);         // N float2
  float* adst1 = (float*)(rec2 + N);
  float* adst2 = adst1 + (size_t)N * HEADS;
  int* rowstart = (int*)(adst2 + N);   // [N+1] padded to N+4
  int* aux      = rowstart + N + 4;    // [<=1024]
  int* bcnt     = aux + 1024;          // [M]
  int* bpart    = bcnt + M;            // [M]
  int* bpre     = bpart + M;           // [M]
  unsigned* bbuf = (unsigned*)(bpre + M);  // [Etot]
  int* csr_src  = (int*)(bbuf + Etot);     // [Etot]
  unsigned short* w2hi = (unsigned short*)(csr_src + Etot);  // [16384]
  unsigned short* w2lo = w2hi + 16384;                       // [16384]

  // ---- W2 fragment pack (independent of everything else) ----
  k_w2pack<<<64, 256, 0, stream>>>(W2, w2hi, w2lo);

  // ---- bucketed CSR build (zero global atomics) ----
  k_hist<<<NBLK, 256, 0, stream>>>(ei, E, Etot, NBK, NBLK, bcnt);
  k_scan1<<<Mblk, 256, 0, stream>>>(bcnt, bpart, aux, M);
  k_scan2<<<1, 512, 0, stream>>>(aux, Mblk);
  k_scan3g<<<Mblk, 256, 0, stream>>>(bpart, aux, bpre, M);
  k_bucket<<<NBLK, 256, 0, stream>>>(ei, bpre, E, Etot, NBK, NBLK, bbuf);
  k_build<<<NBK, 256, 0, stream>>>(bbuf, bpre, rowstart, csr_src, N, Etot,
                                   NBK, NBLK);

  // ---- Layer 1 ----
  k_gemm1<<<(N + 7) / 8, 256, 0, stream>>>(x, W1, a_src1, a_dst1, hq, rec,
                                           adst1, N);
  k_agg1<<<(N + 15) / 16, 256, 0, stream>>>(rowstart, csr_src, rec, adst1, hq,
                                            b1, g1, beta1, x2b, N);

  // ---- Layer 2 ----
  k_gemm2m<<<(N + 127) / 128, 256, 0, stream>>>(x2b, w2hi, w2lo, a_src2,
                                                a_dst2, hq2, rec2, adst2, N);
  k_agg2<<<(N + 15) / 16, 256, 0, stream>>>(rowstart, csr_src, rec2, adst2,
                                            hq2, b2, g2, beta2, out, N);
}

// Round 9
// 311.655 us; speedup vs baseline: 1.0583x; 1.0181x over previous
//
#include <hip/hip_runtime.h>

#define IN_CH 16
#define HID 128
#define HEADS 4
#define NEG 0.2f
#define LN_EPS 1e-5f
#define BCAP 8192  // max edges per 256-node bucket (mean ~4400, +55 sigma)
#define DB 64      // degree bins for node sort

typedef short bf16x8 __attribute__((ext_vector_type(8)));
typedef float f32x4 __attribute__((ext_vector_type(4)));

__device__ __forceinline__ float bf2f(unsigned short u) {
  return __uint_as_float(((unsigned)u) << 16);
}
__device__ __forceinline__ unsigned short f2bf(float f) {
  unsigned u = __float_as_uint(f);
  unsigned r = (u + 0x7fffu + ((u >> 16) & 1u)) >> 16;  // RNE
  return (unsigned short)r;
}
// sign-extended byte -> float. sh in {0,8,16,24}.
__device__ __forceinline__ float sb(unsigned v, int sh) {
  return (float)((int)(v << (24 - sh)) >> 24);
}

// ---------------------------------------------------------------------------
// h1 = x @ W1 -> int8 (per-node scale), fused attention logits.
// rec1h[n*4+h] = {asrc_h, scale} (single 8B gather in agg1).
// ---------------------------------------------------------------------------
__global__ __launch_bounds__(256) void k_gemm1(
    const float* __restrict__ x, const float* __restrict__ W1,
    const float* __restrict__ a_src, const float* __restrict__ a_dst,
    signed char* __restrict__ hq, float2* __restrict__ rec1h,
    float* __restrict__ adst, int N) {
  __shared__ float w1s[IN_CH][HID];
  __shared__ float xsh[8][IN_CH];
  int tid = threadIdx.x;
  int nb = blockIdx.x * 8;
  for (int i = tid; i < IN_CH * HID; i += 256) ((float*)w1s)[i] = W1[i];
  if (tid < 128) {
    int nl = tid >> 4, k = tid & 15;
    int n = nb + nl;
    xsh[nl][k] = (n < N) ? x[n * IN_CH + k] : 0.f;
  }
  __syncthreads();
  int nl = tid >> 5;
  int l32 = tid & 31;
  int c0 = l32 << 2;
  int n = nb + nl;
  float4 acc = make_float4(0.f, 0.f, 0.f, 0.f);
#pragma unroll
  for (int k = 0; k < IN_CH; ++k) {
    float xv = xsh[nl][k];
    float4 wv = *(const float4*)(&w1s[k][c0]);
    acc.x += xv * wv.x;
    acc.y += xv * wv.y;
    acc.z += xv * wv.z;
    acc.w += xv * wv.w;
  }
  float4 as4 = *(const float4*)(a_src + c0);
  float4 ad4 = *(const float4*)(a_dst + c0);
  float av = acc.x * as4.x + acc.y * as4.y + acc.z * as4.z + acc.w * as4.w;
  float dv = acc.x * ad4.x + acc.y * ad4.y + acc.z * ad4.z + acc.w * ad4.w;
  av += __shfl_xor(av, 1);
  av += __shfl_xor(av, 2);
  av += __shfl_xor(av, 4);
  dv += __shfl_xor(dv, 1);
  dv += __shfl_xor(dv, 2);
  dv += __shfl_xor(dv, 4);
  float m = fmaxf(fmaxf(fabsf(acc.x), fabsf(acc.y)),
                  fmaxf(fabsf(acc.z), fabsf(acc.w)));
#pragma unroll
  for (int o = 1; o < 32; o <<= 1) m = fmaxf(m, __shfl_xor(m, o));
  if (n < N) {
    float rs = (m > 0.f) ? 127.f / m : 0.f;
    int b0 = __float2int_rn(acc.x * rs) & 255;
    int b1 = __float2int_rn(acc.y * rs) & 255;
    int b2 = __float2int_rn(acc.z * rs) & 255;
    int b3 = __float2int_rn(acc.w * rs) & 255;
    *(unsigned*)(hq + (size_t)n * HID + c0) =
        (unsigned)(b0 | (b1 << 8) | (b2 << 16) | (b3 << 24));
    if ((l32 & 7) == 0) {
      rec1h[n * 4 + (l32 >> 3)] = make_float2(av, m * (1.f / 127.f));
      adst[n * HEADS + (l32 >> 3)] = dv;
    }
  }
}

// ---------------------------------------------------------------------------
// CSR build, pass A: per-(bucket, block) histogram. (R5-verified)
// ---------------------------------------------------------------------------
__global__ __launch_bounds__(256) void k_hist(
    const int* __restrict__ ei, int E, int Etot, int NBK, int NBLK,
    int* __restrict__ bcnt) {
  __shared__ int lh[512];
  int blk = blockIdx.x;
  for (int i = threadIdx.x; i < 512; i += 256) lh[i] = 0;
  __syncthreads();
  int s0 = blk * 8192, s1 = min(s0 + 8192, Etot);
  for (int e = s0 + threadIdx.x; e < s1; e += 256) {
    int d = (e < E) ? ei[E + e] : (e - E);
    atomicAdd(&lh[d >> 8], 1);
  }
  __syncthreads();
  for (int i = threadIdx.x; i < NBK; i += 256) bcnt[i * NBLK + blk] = lh[i];
}

__global__ __launch_bounds__(256) void k_scan1(
    const int* __restrict__ deg, int* __restrict__ part, int* __restrict__ aux,
    int N) {
  int i = blockIdx.x * 256 + threadIdx.x;
  int v = (i < N) ? deg[i] : 0;
  int lane = threadIdx.x & 63, w = threadIdx.x >> 6;
  int inc = v;
#pragma unroll
  for (int o = 1; o < 64; o <<= 1) {
    int t = __shfl_up(inc, o, 64);
    if (lane >= o) inc += t;
  }
  __shared__ int wsum[4];
  if (lane == 63) wsum[w] = inc;
  __syncthreads();
  int woff = 0;
#pragma unroll
  for (int k = 0; k < 4; ++k)
    if (k < w) woff += wsum[k];
  if (i < N) part[i] = woff + inc - v;
  if (threadIdx.x == 255) aux[blockIdx.x] = woff + inc;
}

__global__ __launch_bounds__(512) void k_scan2(int* __restrict__ aux, int nb) {
  int i = threadIdx.x;
  int v = (i < nb) ? aux[i] : 0;
  int lane = i & 63, w = i >> 6;
  int inc = v;
#pragma unroll
  for (int o = 1; o < 64; o <<= 1) {
    int t = __shfl_up(inc, o, 64);
    if (lane >= o) inc += t;
  }
  __shared__ int wsum[8];
  if (lane == 63) wsum[w] = inc;
  __syncthreads();
  int woff = 0;
#pragma unroll
  for (int k = 0; k < 8; ++k)
    if (k < w) woff += wsum[k];
  if (i < nb) aux[i] = woff + inc - v;
}

__global__ __launch_bounds__(256) void k_scan3g(
    const int* __restrict__ part, const int* __restrict__ aux,
    int* __restrict__ out, int M) {
  int i = blockIdx.x * 256 + threadIdx.x;
  if (i < M) out[i] = part[i] + aux[blockIdx.x];
}

// ---------------------------------------------------------------------------
// CSR build, pass C: bucket-contiguous placement. (R5-verified)
// ---------------------------------------------------------------------------
__global__ __launch_bounds__(256) void k_bucket(
    const int* __restrict__ ei, const int* __restrict__ bpre, int E, int Etot,
    int NBK, int NBLK, unsigned* __restrict__ bbuf) {
  __shared__ int lc[512];
  int blk = blockIdx.x;
  for (int i = threadIdx.x; i < NBK; i += 256) lc[i] = bpre[i * NBLK + blk];
  __syncthreads();
  int s0 = blk * 8192, s1 = min(s0 + 8192, Etot);
  for (int e = s0 + threadIdx.x; e < s1; e += 256) {
    int d = (e < E) ? ei[E + e] : (e - E);
    int s = (e < E) ? ei[e] : d;
    int pos = atomicAdd(&lc[d >> 8], 1);
    bbuf[pos] = ((unsigned)s << 8) | (unsigned)(d & 255);
  }
}

// ---------------------------------------------------------------------------
// CSR build, pass D: per-bucket LDS sort -> rowstart + coalesced csr_src.
// Also emits a per-bucket degree histogram (64 bins) for the node sort.
// ---------------------------------------------------------------------------
__global__ __launch_bounds__(256) void k_build(
    const unsigned* __restrict__ bbuf, const int* __restrict__ bpre,
    int* __restrict__ rowstart, int* __restrict__ csr_src,
    int* __restrict__ dcnt, int N, int Etot, int NBK, int NBLK) {
  __shared__ int ldeg[256], lcur[256], wsum[4], ldh[DB];
  __shared__ int lout[BCAP];
  int bin = blockIdx.x;
  int base = bpre[bin * NBLK];
  int next = (bin + 1 < NBK) ? bpre[(bin + 1) * NBLK] : Etot;
  int cnt = next - base;
  if (cnt > BCAP) cnt = BCAP;
  int tid = threadIdx.x;
  ldeg[tid] = 0;
  if (tid < DB) ldh[tid] = 0;
  __syncthreads();
  for (int i = tid; i < cnt; i += 256)
    atomicAdd(&ldeg[bbuf[base + i] & 255u], 1);
  __syncthreads();
  int v = ldeg[tid];
  int lane = tid & 63, wv = tid >> 6;
  int inc = v;
#pragma unroll
  for (int o = 1; o < 64; o <<= 1) {
    int t = __shfl_up(inc, o, 64);
    if (lane >= o) inc += t;
  }
  if (lane == 63) wsum[wv] = inc;
  __syncthreads();
  int woff = 0;
#pragma unroll
  for (int k = 0; k < 4; ++k)
    if (k < wv) woff += wsum[k];
  int pre = woff + inc - v;
  int node = bin * 256 + tid;
  if (node < N) {
    rowstart[node] = base + pre;
    atomicAdd(&ldh[min(v, DB - 1)], 1);
  }
  lcur[tid] = pre;
  __syncthreads();
  for (int i = tid; i < cnt; i += 256) {
    unsigned u = bbuf[base + i];
    int p = atomicAdd(&lcur[u & 255u], 1);
    lout[p] = (int)(u >> 8);
  }
  __syncthreads();
  for (int i = tid; i < cnt; i += 256) csr_src[base + i] = lout[i];
  if (tid < DB) dcnt[tid * NBK + bin] = ldh[tid];
  if (bin == 0 && tid == 0) rowstart[N] = Etot;
}

// ---------------------------------------------------------------------------
// Node sort pass: place nodes into degree-sorted permutation (counting sort
// by exact degree for deg<63; bin 63 holds the rare heavy tail).
// ---------------------------------------------------------------------------
__global__ __launch_bounds__(256) void k_dplace(
    const int* __restrict__ rowstart, const int* __restrict__ dpre, int N,
    int NBK, int* __restrict__ perm) {
  __shared__ int lc[DB];
  int blk = blockIdx.x;
  int tid = threadIdx.x;
  if (tid < DB) lc[tid] = dpre[tid * NBK + blk];
  __syncthreads();
  int n = blk * 256 + tid;
  if (n < N) {
    int deg = rowstart[n + 1] - rowstart[n];
    int b = min(deg, DB - 1);
    int pos = atomicAdd(&lc[b], 1);
    perm[pos] = n;
  }
}

// ---------------------------------------------------------------------------
// Fused GAT agg + bias + ELU + LN, layer 1 (4 heads). int8 payload.
// R6-verified body; node order via degree-sorted perm (uniform wave degree).
// ---------------------------------------------------------------------------
__global__ __launch_bounds__(256) void k_agg1(
    const int* __restrict__ perm, const int* __restrict__ rowstart,
    const int* __restrict__ csr_src, const float2* __restrict__ rec1h,
    const float* __restrict__ adst, const signed char* __restrict__ hq,
    const float* __restrict__ bias, const float* __restrict__ g,
    const float* __restrict__ beta, unsigned short* __restrict__ outb, int N) {
  int gid = blockIdx.x * 16 + (threadIdx.x >> 4);
  if (gid >= N) return;
  int d = perm[gid];
  int lane = threadIdx.x & 15;
  int c0 = lane << 3;  // 8 channels per lane
  int hd = lane >> 2;  // head = c0/32
  float ad = adst[d * HEADS + hd];
  int beg = rowstart[d], end = rowstart[d + 1];
  float a0 = 0.f, a1 = 0.f, a2 = 0.f, a3 = 0.f;
  float a4 = 0.f, a5 = 0.f, a6 = 0.f, a7 = 0.f, wsum = 0.f;
  for (int i = beg; i < end; i += 8) {
    int s[8];
#pragma unroll
    for (int j = 0; j < 8; ++j) {
      int e = i + j;
      s[j] = csr_src[e < end ? e : end - 1];
    }
    float2 r[8];
    uint2 p[8];
#pragma unroll
    for (int j = 0; j < 8; ++j) r[j] = rec1h[s[j] * 4 + hd];
#pragma unroll
    for (int j = 0; j < 8; ++j)
      p[j] = *(const uint2*)(hq + (size_t)s[j] * HID + c0);
#pragma unroll
    for (int j = 0; j < 8; ++j) {
      float v = r[j].x + ad;
      v = v < 0.f ? NEG * v : v;
      float ex = __expf(v);
      float w = (i + j < end) ? ex : 0.f;
      wsum += w;
      float ws = w * r[j].y;
      a0 += ws * sb(p[j].x, 0);
      a1 += ws * sb(p[j].x, 8);
      a2 += ws * sb(p[j].x, 16);
      a3 += ws * sb(p[j].x, 24);
      a4 += ws * sb(p[j].y, 0);
      a5 += ws * sb(p[j].y, 8);
      a6 += ws * sb(p[j].y, 16);
      a7 += ws * sb(p[j].y, 24);
    }
  }
  float rw = 1.f / wsum;
  float v0 = a0 * rw + bias[c0 + 0];
  float v1 = a1 * rw + bias[c0 + 1];
  float v2 = a2 * rw + bias[c0 + 2];
  float v3 = a3 * rw + bias[c0 + 3];
  float v4 = a4 * rw + bias[c0 + 4];
  float v5 = a5 * rw + bias[c0 + 5];
  float v6 = a6 * rw + bias[c0 + 6];
  float v7 = a7 * rw + bias[c0 + 7];
  v0 = v0 > 0.f ? v0 : (__expf(v0) - 1.f);
  v1 = v1 > 0.f ? v1 : (__expf(v1) - 1.f);
  v2 = v2 > 0.f ? v2 : (__expf(v2) - 1.f);
  v3 = v3 > 0.f ? v3 : (__expf(v3) - 1.f);
  v4 = v4 > 0.f ? v4 : (__expf(v4) - 1.f);
  v5 = v5 > 0.f ? v5 : (__expf(v5) - 1.f);
  v6 = v6 > 0.f ? v6 : (__expf(v6) - 1.f);
  v7 = v7 > 0.f ? v7 : (__expf(v7) - 1.f);
  float s1 = ((v0 + v1) + (v2 + v3)) + ((v4 + v5) + (v6 + v7));
  float s2 = ((v0 * v0 + v1 * v1) + (v2 * v2 + v3 * v3)) +
             ((v4 * v4 + v5 * v5) + (v6 * v6 + v7 * v7));
#pragma unroll
  for (int o = 8; o > 0; o >>= 1) {
    s1 += __shfl_down(s1, o, 16);
    s2 += __shfl_down(s2, o, 16);
  }
  s1 = __shfl(s1, 0, 16);
  s2 = __shfl(s2, 0, 16);
  float mu = s1 * (1.f / HID);
  float var = s2 * (1.f / HID) - mu * mu;
  float inv = rsqrtf(var + LN_EPS);
  ushort4 q0, q1;
  q0.x = f2bf((v0 - mu) * inv * g[c0 + 0] + beta[c0 + 0]);
  q0.y = f2bf((v1 - mu) * inv * g[c0 + 1] + beta[c0 + 1]);
  q0.z = f2bf((v2 - mu) * inv * g[c0 + 2] + beta[c0 + 2]);
  q0.w = f2bf((v3 - mu) * inv * g[c0 + 3] + beta[c0 + 3]);
  q1.x = f2bf((v4 - mu) * inv * g[c0 + 4] + beta[c0 + 4]);
  q1.y = f2bf((v5 - mu) * inv * g[c0 + 5] + beta[c0 + 5]);
  q1.z = f2bf((v6 - mu) * inv * g[c0 + 6] + beta[c0 + 6]);
  q1.w = f2bf((v7 - mu) * inv * g[c0 + 7] + beta[c0 + 7]);
  *(ushort4*)(outb + (size_t)d * HID + c0) = q0;
  *(ushort4*)(outb + (size_t)d * HID + c0 + 4) = q1;
}

// ---------------------------------------------------------------------------
// Fused GAT agg + bias + ELU + LN, layer 2 (1 head). int8 payload,
// rec2 = {asrc, scale}. R6-verified body + degree-sorted perm.
// ---------------------------------------------------------------------------
__global__ __launch_bounds__(256) void k_agg2(
    const int* __restrict__ perm, const int* __restrict__ rowstart,
    const int* __restrict__ csr_src, const float2* __restrict__ rec2,
    const float* __restrict__ adst, const signed char* __restrict__ hq2,
    const float* __restrict__ bias, const float* __restrict__ g,
    const float* __restrict__ beta, float* __restrict__ out, int N) {
  int gid = blockIdx.x * 16 + (threadIdx.x >> 4);
  if (gid >= N) return;
  int d = perm[gid];
  int lane = threadIdx.x & 15;
  int c0 = lane << 3;
  float ad = adst[d];
  int beg = rowstart[d], end = rowstart[d + 1];
  float a0 = 0.f, a1 = 0.f, a2 = 0.f, a3 = 0.f;
  float a4 = 0.f, a5 = 0.f, a6 = 0.f, a7 = 0.f, wsum = 0.f;
  for (int i = beg; i < end; i += 8) {
    int s[8];
#pragma unroll
    for (int j = 0; j < 8; ++j) {
      int e = i + j;
      s[j] = csr_src[e < end ? e : end - 1];
    }
    float2 r[8];
    uint2 p[8];
#pragma unroll
    for (int j = 0; j < 8; ++j) r[j] = rec2[s[j]];
#pragma unroll
    for (int j = 0; j < 8; ++j)
      p[j] = *(const uint2*)(hq2 + (size_t)s[j] * HID + c0);
#pragma unroll
    for (int j = 0; j < 8; ++j) {
      float v = r[j].x + ad;
      v = v < 0.f ? NEG * v : v;
      float ex = __expf(v);
      float w = (i + j < end) ? ex : 0.f;
      wsum += w;
      float ws = w * r[j].y;
      a0 += ws * sb(p[j].x, 0);
      a1 += ws * sb(p[j].x, 8);
      a2 += ws * sb(p[j].x, 16);
      a3 += ws * sb(p[j].x, 24);
      a4 += ws * sb(p[j].y, 0);
      a5 += ws * sb(p[j].y, 8);
      a6 += ws * sb(p[j].y, 16);
      a7 += ws * sb(p[j].y, 24);
    }
  }
  float rw = 1.f / wsum;
  float v0 = a0 * rw + bias[c0 + 0];
  float v1 = a1 * rw + bias[c0 + 1];
  float v2 = a2 * rw + bias[c0 + 2];
  float v3 = a3 * rw + bias[c0 + 3];
  float v4 = a4 * rw + bias[c0 + 4];
  float v5 = a5 * rw + bias[c0 + 5];
  float v6 = a6 * rw + bias[c0 + 6];
  float v7 = a7 * rw + bias[c0 + 7];
  v0 = v0 > 0.f ? v0 : (__expf(v0) - 1.f);
  v1 = v1 > 0.f ? v1 : (__expf(v1) - 1.f);
  v2 = v2 > 0.f ? v2 : (__expf(v2) - 1.f);
  v3 = v3 > 0.f ? v3 : (__expf(v3) - 1.f);
  v4 = v4 > 0.f ? v4 : (__expf(v4) - 1.f);
  v5 = v5 > 0.f ? v5 : (__expf(v5) - 1.f);
  v6 = v6 > 0.f ? v6 : (__expf(v6) - 1.f);
  v7 = v7 > 0.f ? v7 : (__expf(v7) - 1.f);
  float s1 = ((v0 + v1) + (v2 + v3)) + ((v4 + v5) + (v6 + v7));
  float s2 = ((v0 * v0 + v1 * v1) + (v2 * v2 + v3 * v3)) +
             ((v4 * v4 + v5 * v5) + (v6 * v6 + v7 * v7));
#pragma unroll
  for (int o = 8; o > 0; o >>= 1) {
    s1 += __shfl_down(s1, o, 16);
    s2 += __shfl_down(s2, o, 16);
  }
  s1 = __shfl(s1, 0, 16);
  s2 = __shfl(s2, 0, 16);
  float mu = s1 * (1.f / HID);
  float var = s2 * (1.f / HID) - mu * mu;
  float inv = rsqrtf(var + LN_EPS);
  float4 o0, o1;
  o0.x = (v0 - mu) * inv * g[c0 + 0] + beta[c0 + 0];
  o0.y = (v1 - mu) * inv * g[c0 + 1] + beta[c0 + 1];
  o0.z = (v2 - mu) * inv * g[c0 + 2] + beta[c0 + 2];
  o0.w = (v3 - mu) * inv * g[c0 + 3] + beta[c0 + 3];
  o1.x = (v4 - mu) * inv * g[c0 + 4] + beta[c0 + 4];
  o1.y = (v5 - mu) * inv * g[c0 + 5] + beta[c0 + 5];
  o1.z = (v6 - mu) * inv * g[c0 + 6] + beta[c0 + 6];
  o1.w = (v7 - mu) * inv * g[c0 + 7] + beta[c0 + 7];
  *(float4*)(out + (size_t)d * HID + c0) = o0;
  *(float4*)(out + (size_t)d * HID + c0 + 4) = o1;
}

// ---------------------------------------------------------------------------
// Pack W2 into MFMA B-fragment order, bf16 hi+lo. (R1-verified)
// ---------------------------------------------------------------------------
__global__ __launch_bounds__(256) void k_w2pack(
    const float* __restrict__ W2, unsigned short* __restrict__ w2hi,
    unsigned short* __restrict__ w2lo) {
  int idx = blockIdx.x * 256 + threadIdx.x;  // 16384 total
  int i = idx & 7;
  int lane = (idx >> 3) & 63;
  int t = (idx >> 9) & 7;
  int kb = idx >> 12;
  int k = kb * 32 + (lane >> 4) * 8 + i;
  int c = t * 16 + (lane & 15);
  float w = W2[k * HID + c];
  unsigned short hi = f2bf(w);
  float res = w - bf2f(hi);
  w2hi[idx] = hi;
  w2lo[idx] = f2bf(res);
}

// ---------------------------------------------------------------------------
// h2 = x2 @ W2 via MFMA bf16 (hi+lo split). Epilogue quantizes h2 -> int8
// per-node scale + rec2 = {asrc2, scale}; adst2 separate. (R6-verified)
// ---------------------------------------------------------------------------
__global__ __launch_bounds__(256) void k_gemm2m(
    const unsigned short* __restrict__ x2b,
    const unsigned short* __restrict__ w2hi,
    const unsigned short* __restrict__ w2lo,
    const float* __restrict__ a_src, const float* __restrict__ a_dst,
    signed char* __restrict__ hq2, float2* __restrict__ rec2,
    float* __restrict__ adst, int N) {
  __shared__ float cs[4][16][132];
  int w = threadIdx.x >> 6;
  int l = threadIdx.x & 63;
  int n0 = blockIdx.x * 128 + w * 32;
  int m = l & 15;    // A row within tile
  int kg = l >> 4;   // k-group
  int naA = n0 + m;
  if (naA >= N) naA = N - 1;  // clamp loads; garbage rows never stored
  int naB = n0 + 16 + m;
  if (naB >= N) naB = N - 1;
  const unsigned short* xA = x2b + (size_t)naA * HID + kg * 8;
  const unsigned short* xB = x2b + (size_t)naB * HID + kg * 8;
  f32x4 accA[8] = {};
  f32x4 accB[8] = {};
#pragma unroll
  for (int kb = 0; kb < 4; ++kb) {
    bf16x8 aA = *(const bf16x8*)(xA + kb * 32);
    bf16x8 aB = *(const bf16x8*)(xB + kb * 32);
#pragma unroll
    for (int t = 0; t < 8; ++t) {
      bf16x8 bl = *(const bf16x8*)(w2lo + ((kb * 8 + t) * 64 + l) * 8);
      bf16x8 bh = *(const bf16x8*)(w2hi + ((kb * 8 + t) * 64 + l) * 8);
      accA[t] = __builtin_amdgcn_mfma_f32_16x16x32_bf16(aA, bl, accA[t], 0, 0, 0);
      accA[t] = __builtin_amdgcn_mfma_f32_16x16x32_bf16(aA, bh, accA[t], 0, 0, 0);
      accB[t] = __builtin_amdgcn_mfma_f32_16x16x32_bf16(aB, bl, accB[t], 0, 0, 0);
      accB[t] = __builtin_amdgcn_mfma_f32_16x16x32_bf16(aB, bh, accB[t], 0, 0, 0);
    }
  }
  // C/D layout (measured): col = lane&15, row = (lane>>4)*4 + reg.
  auto epilog = [&](const f32x4(&acc)[8], int noff) {
#pragma unroll
    for (int t = 0; t < 8; ++t)
#pragma unroll
      for (int j = 0; j < 4; ++j) cs[w][kg * 4 + j][t * 16 + m] = acc[t][j];
    __syncthreads();
    int r2 = l & 15;
    int q = l >> 4;
    int n = n0 + noff + r2;
    const float* rowp = &cs[w][r2][0];
    float4 v[8];
    float pa = 0.f, pd = 0.f, mx = 0.f;
#pragma unroll
    for (int j = 0; j < 8; ++j) {
      int cc = q * 32 + j * 4;
      v[j] = *(const float4*)(rowp + cc);
      float4 as = *(const float4*)(a_src + cc);
      float4 av = *(const float4*)(a_dst + cc);
      pa += v[j].x * as.x + v[j].y * as.y + v[j].z * as.z + v[j].w * as.w;
      pd += v[j].x * av.x + v[j].y * av.y + v[j].z * av.z + v[j].w * av.w;
      mx = fmaxf(mx, fmaxf(fmaxf(fabsf(v[j].x), fabsf(v[j].y)),
                           fmaxf(fabsf(v[j].z), fabsf(v[j].w))));
    }
    pa += __shfl_xor(pa, 16);
    pa += __shfl_xor(pa, 32);
    pd += __shfl_xor(pd, 16);
    pd += __shfl_xor(pd, 32);
    mx = fmaxf(mx, __shfl_xor(mx, 16));
    mx = fmaxf(mx, __shfl_xor(mx, 32));
    if (n < N) {
      float rs = (mx > 0.f) ? 127.f / mx : 0.f;
      unsigned u[8];
#pragma unroll
      for (int j = 0; j < 8; ++j) {
        int b0 = __float2int_rn(v[j].x * rs) & 255;
        int b1 = __float2int_rn(v[j].y * rs) & 255;
        int b2 = __float2int_rn(v[j].z * rs) & 255;
        int b3 = __float2int_rn(v[j].w * rs) & 255;
        u[j] = (unsigned)(b0 | (b1 << 8) | (b2 << 16) | (b3 << 24));
      }
      *(uint4*)(hq2 + (size_t)n * HID + q * 32) =
          make_uint4(u[0], u[1], u[2], u[3]);
      *(uint4*)(hq2 + (size_t)n * HID + q * 32 + 16) =
          make_uint4(u[4], u[5], u[6], u[7]);
      if (q == 0) {
        rec2[n] = make_float2(pa, mx * (1.f / 127.f));
        adst[n] = pd;
      }
    }
    __syncthreads();
  };
  epilog(accA, 0);
  epilog(accB, 16);
}

extern "C" void kernel_launch(void* const* d_in, const int* in_sizes, int n_in,
                              void* d_out, int out_size, void* d_ws, size_t ws_size,
                              hipStream_t stream) {
  const float* x      = (const float*)d_in[0];
  const int*   ei     = (const int*)d_in[1];
  const float* W1     = (const float*)d_in[2];
  const float* a_src1 = (const float*)d_in[3];
  const float* a_dst1 = (const float*)d_in[4];
  const float* b1     = (const float*)d_in[5];
  const float* g1     = (const float*)d_in[6];
  const float* beta1  = (const float*)d_in[7];
  const float* W2     = (const float*)d_in[8];
  const float* a_src2 = (const float*)d_in[9];
  const float* a_dst2 = (const float*)d_in[10];
  const float* b2     = (const float*)d_in[11];
  const float* g2     = (const float*)d_in[12];
  const float* beta2  = (const float*)d_in[13];
  float* out = (float*)d_out;

  const int N = in_sizes[0] / IN_CH;
  const int E = in_sizes[1] / 2;
  const int Etot = E + N;

  // bucketed CSR geometry
  const int NBK = (N + 255) >> 8;          // buckets of 256 nodes
  const int NBLK = (Etot + 8191) >> 13;    // 8192-edge chunks
  const int M = NBK * NBLK;                // edge count-matrix size
  const int Mblk = (M + 255) / 256;        // scan blocks (<= 512)
  const int M2 = DB * NBK;                 // degree count-matrix size
  const int M2blk = (M2 + 255) / 256;

  // workspace layout (separate regions; no overlays)
  unsigned char* U = (unsigned char*)d_ws;
  signed char* hq = (signed char*)U;                       // N*HID int8
  float2* rec1h = (float2*)(U + (size_t)N * HID);          // N*4 float2
  unsigned short* x2b =
      (unsigned short*)(U + (size_t)N * HID + (size_t)N * 32);  // N*HID bf16
  signed char* hq2 = (signed char*)(x2b + (size_t)N * HID);     // N*HID int8
  float2* rec2 = (float2*)(hq2 + (size_t)N * HID);         // N float2
  float* adst1 = (float*)(rec2 + N);
  float* adst2 = adst1 + (size_t)N * HEADS;
  int* rowstart = (int*)(adst2 + N);   // [N+1] padded to N+4
  int* aux      = rowstart + N + 4;    // [<=1024]
  int* bcnt     = aux + 1024;          // [M] (reused as dcnt after k_build)
  int* bpart    = bcnt + M;            // [M] (reused as dpart)
  int* bpre     = bpart + M;           // [M] (reused as dpre)
  unsigned* bbuf = (unsigned*)(bpre + M);  // [Etot]
  int* csr_src  = (int*)(bbuf + Etot);     // [Etot]
  unsigned short* w2hi = (unsigned short*)(csr_src + Etot);  // [16384]
  unsigned short* w2lo = w2hi + 16384;                       // [16384]
  int* perm = (int*)(w2lo + 16384);                          // [N]

  // ---- W2 fragment pack (independent of everything else) ----
  k_w2pack<<<64, 256, 0, stream>>>(W2, w2hi, w2lo);

  // ---- bucketed CSR build (zero global atomics) ----
  k_hist<<<NBLK, 256, 0, stream>>>(ei, E, Etot, NBK, NBLK, bcnt);
  k_scan1<<<Mblk, 256, 0, stream>>>(bcnt, bpart, aux, M);
  k_scan2<<<1, 512, 0, stream>>>(aux, Mblk);
  k_scan3g<<<Mblk, 256, 0, stream>>>(bpart, aux, bpre, M);
  k_bucket<<<NBLK, 256, 0, stream>>>(ei, bpre, E, Etot, NBK, NBLK, bbuf);
  k_build<<<NBK, 256, 0, stream>>>(bbuf, bpre, rowstart, csr_src, bcnt, N,
                                   Etot, NBK, NBLK);

  // ---- degree-sorted node permutation (bcnt/bpart/bpre reused) ----
  k_scan1<<<M2blk, 256, 0, stream>>>(bcnt, bpart, aux, M2);
  k_scan2<<<1, 512, 0, stream>>>(aux, M2blk);
  k_scan3g<<<M2blk, 256, 0, stream>>>(bpart, aux, bpre, M2);
  k_dplace<<<NBK, 256, 0, stream>>>(rowstart, bpre, N, NBK, perm);

  // ---- Layer 1 ----
  k_gemm1<<<(N + 7) / 8, 256, 0, stream>>>(x, W1, a_src1, a_dst1, hq, rec1h,
                                           adst1, N);
  k_agg1<<<(N + 15) / 16, 256, 0, stream>>>(perm, rowstart, csr_src, rec1h,
                                            adst1, hq, b1, g1, beta1, x2b, N);

  // ---- Layer 2 ----
  k_gemm2m<<<(N + 127) / 128, 256, 0, stream>>>(x2b, w2hi, w2lo, a_src2,
                                                a_dst2, hq2, rec2, adst2, N);
  k_agg2<<<(N + 15) / 16, 256, 0, stream>>>(perm, rowstart, csr_src, rec2,
                                            adst2, hq2, b2, g2, beta2, out, N);
}